// Round 13
// baseline (1153.252 us; speedup 1.0000x reference)
//
#include <hip/hip_runtime.h>
#include <math.h>

namespace {

constexpr int B_  = 2048;
constexpr int T_  = 100;
constexpr int D_  = 128;
constexpr int BT_ = B_ * T_;     // 204800
constexpr int M_  = 64;          // rows per block

using f32x4  = __attribute__((ext_vector_type(4))) float;
using bf16x8 = __attribute__((ext_vector_type(8))) __bf16;

enum { MODE_ENC = 0, MODE_ID = 1, MODE_TANH = 2 };

// Manual RNE f32->bf16. R9 lesson: v_cvt_pk_bf16_f32 is NOT round-nearest-even
// here (absmax 0.002 -> 0.091, within 9% of the fail threshold). Keep manual.
__device__ __forceinline__ unsigned short f2bf(float f) {
  unsigned int u = __float_as_uint(f);
  return (unsigned short)((u + 0x7FFFu + ((u >> 16) & 1u)) >> 16);
}
__device__ __forceinline__ unsigned int pack2(float a, float b) {
  return (unsigned int)f2bf(a) | ((unsigned int)f2bf(b) << 16);
}
__device__ __forceinline__ float ftanh(float x) {   // feeds bf16; err ~1e-6 << bf16 ulp
  const float e = __expf(2.0f * x);
  return 1.0f - 2.0f / (e + 1.0f);
}

// ---- swapped-operand MFMA GEMM, wide-N waves ----------------------------
// out[r][c] = sum_k act[r][k] * W[c][k] via mfma(A-op=W, B-op=act):
// D col(lane&15)=act-row, D row(lk*4+j)=W-col. R13 remap: wave = (colgroup
// wave&3) x (rowgroup wave>>2): NT col-tiles x NSUB row-subtiles with
// NT>=NSUB -> A-fragment ds_reads per MFMA drop by NT/NSUB vs R11's 2x4
// (halves the LDS A-read traffic that dominated the R11 block wall; MFMA
// count unchanged). W-loads double but hit L1 (co-resident waves).
// A: bf16 rows in LDS, stride astr, 16B slots XOR-swizzled by ((row&15)<<4).
// Wt: bf16 [col][KFW] pre-offset to this wave's col0. acc[nt][s]: col-tile
// nt (16 cols), act-rows rowbase+s*16..+16.
template <int KGEMM, int NT, int NSUB, int KFW>
__device__ __forceinline__ void gemm(const char* __restrict__ A, const int astr,
                                     const unsigned short* __restrict__ Wt,
                                     f32x4 (&acc)[NT][NSUB], const int rowbase,
                                     const int lrow, const int lk) {
  constexpr int NK = KGEMM / 32;
  const int key = lrow << 4;
  const unsigned short* wl = Wt + lk * 8;        // lane's k-phase
#pragma unroll
  for (int kk = 0; kk < NK; ++kk) {
    int4 breg[NT];
#pragma unroll
    for (int nt = 0; nt < NT; ++nt)
      breg[nt] = *reinterpret_cast<const int4*>(
          wl + (size_t)(nt * 16 + lrow) * KFW + kk * 32);
    bf16x8 act[NSUB];
#pragma unroll
    for (int s = 0; s < NSUB; ++s)
      act[s] = __builtin_bit_cast(bf16x8,
          *reinterpret_cast<const int4*>(A + (rowbase + s * 16 + lrow) * astr + ((kk * 64 + lk * 16) ^ key)));
#pragma unroll
    for (int nt = 0; nt < NT; ++nt) {
      const bf16x8 w = __builtin_bit_cast(bf16x8, breg[nt]);
#pragma unroll
      for (int s = 0; s < NSUB; ++s)
        acc[nt][s] = __builtin_amdgcn_mfma_f32_16x16x32_bf16(w, act[s], acc[nt][s], 0, 0, 0);
    }
  }
}

// bias[col]: lane's 4 acc elems are 4 consecutive cols -> float4 load.
template <int NT, int NSUB>
__device__ __forceinline__ void init_bias(f32x4 (&acc)[NT][NSUB], const float* __restrict__ bias,
                                          const int lk) {
#pragma unroll
  for (int nt = 0; nt < NT; ++nt) {
    const f32x4 bv = *reinterpret_cast<const f32x4*>(bias + nt * 16 + lk * 4);
#pragma unroll
    for (int s = 0; s < NSUB; ++s) acc[nt][s] = bv;
  }
}

// (relu?) + RNE bf16 pack + 8B LDS store (row stride strideB, swizzled).
template <int NT, int NSUB, bool RELU>
__device__ __forceinline__ void store_lds_pk(char* __restrict__ dst, const int strideB,
                                             const int colLocal0, f32x4 (&acc)[NT][NSUB],
                                             const int rowbase, const int lrow, const int lk) {
  const int key = lrow << 4;
#pragma unroll
  for (int nt = 0; nt < NT; ++nt) {
    const int colb = (colLocal0 + nt * 16 + lk * 4) * 2;
#pragma unroll
    for (int s = 0; s < NSUB; ++s) {
      float v0 = acc[nt][s][0], v1 = acc[nt][s][1], v2 = acc[nt][s][2], v3 = acc[nt][s][3];
      if (RELU) {
        v0 = fmaxf(v0, 0.f); v1 = fmaxf(v1, 0.f); v2 = fmaxf(v2, 0.f); v3 = fmaxf(v3, 0.f);
      }
      uint2 w;
      w.x = pack2(v0, v1);
      w.y = pack2(v2, v3);
      *reinterpret_cast<uint2*>(dst + (rowbase + s * 16 + lrow) * strideB + (colb ^ key)) = w;
    }
  }
}

template <int MODE>
__device__ __forceinline__ int rowmap(const int rl) {
  if constexpr (MODE == MODE_TANH) {
    const int b = rl / 99;
    return b * T_ + (rl - b * 99) + 1;
  }
  return rl;
}

// final layer: lane's 4 cols contiguous -> direct float4 global stores.
template <int MODE, int NT, int NSUB>
__device__ __forceinline__ void store_global(float* __restrict__ gout, f32x4 (&acc)[NT][NSUB],
                                             const int r0, const int col0, const int rowbase,
                                             const int lrow, const int lk) {
#pragma unroll
  for (int s = 0; s < NSUB; ++s) {
    const int g = rowmap<MODE>(r0 + rowbase + s * 16 + lrow);
    float* gr = gout + (size_t)g * D_ + col0 + lk * 4;
#pragma unroll
    for (int nt = 0; nt < NT; ++nt)
      *reinterpret_cast<float4*>(gr + nt * 16) = __builtin_bit_cast(float4, acc[nt][s]);
  }
}

// stage 64 rows x 128 f32 -> bf16 LDS (stride 256B, swizzled); 512 threads.
template <int MODE>
__device__ __forceinline__ void stage(const float* __restrict__ in, char* __restrict__ X,
                                      float* __restrict__ xpred0,
                                      const int r0, const int tid) {
#pragma unroll
  for (int i = 0; i < 2; ++i) {
    const int c   = tid + i * 512;   // 1024 chunks of 8 floats
    const int row = c >> 4;
    const int cb  = c & 15;
    const int rl  = r0 + row;
    const int g   = rowmap<MODE>(rl);
    const float4* gp = reinterpret_cast<const float4*>(in + (size_t)g * D_ + cb * 8);
    float4 v0 = gp[0], v1 = gp[1];
    if constexpr (MODE == MODE_ENC) {
      v0.x = (v0.x == v0.x) ? v0.x : 0.f;  v0.y = (v0.y == v0.y) ? v0.y : 0.f;
      v0.z = (v0.z == v0.z) ? v0.z : 0.f;  v0.w = (v0.w == v0.w) ? v0.w : 0.f;
      v1.x = (v1.x == v1.x) ? v1.x : 0.f;  v1.y = (v1.y == v1.y) ? v1.y : 0.f;
      v1.z = (v1.z == v1.z) ? v1.z : 0.f;  v1.w = (v1.w == v1.w) ? v1.w : 0.f;
      if (rl % T_ == 0) {   // x_pred[:,0,:] = cleaned x[:,0,:]
        float4* xp = reinterpret_cast<float4*>(xpred0 + (size_t)g * D_ + cb * 8);
        xp[0] = v0; xp[1] = v1;
      }
    }
    if constexpr (MODE == MODE_TANH) {
      v0.x = ftanh(v0.x); v0.y = ftanh(v0.y); v0.z = ftanh(v0.z); v0.w = ftanh(v0.w);
      v1.x = ftanh(v1.x); v1.y = ftanh(v1.y); v1.z = ftanh(v1.z); v1.w = ftanh(v1.w);
    }
    int4 pk;
    pk.x = (int)pack2(v0.x, v0.y); pk.y = (int)pack2(v0.z, v0.w);
    pk.z = (int)pack2(v1.x, v1.y); pk.w = (int)pack2(v1.z, v1.w);
    *reinterpret_cast<int4*>(X + row * 256 + ((cb * 16) ^ ((row & 15) << 4))) = pk;
  }
}

// ---- decoder body: input bf16 in Bs (stride 256) -> gout rows rowmap -----
// 128 -> 256(relu ->Aa) -> 512(relu, 2 halves ->Bs) -> 128 (K-accumulate).
// Entry condition: all waves past a barrier AFTER their last Aa read.
template <int MODE>
__device__ __forceinline__ void dec_body(const unsigned short* __restrict__ dW0t, const float* __restrict__ d_b0,
                                         const unsigned short* __restrict__ dW1t, const float* __restrict__ d_b1,
                                         const unsigned short* __restrict__ dW2t, const float* __restrict__ d_b2,
                                         float* __restrict__ gout,
                                         char* __restrict__ Aa, char* __restrict__ Bs,
                                         const int r0, const int wave, const int lrow, const int lk) {
  const int wc = wave & 3;            // col-group
  const int wr = (wave >> 2) * 32;    // row-group base

  f32x4 acc1[4][2];
  init_bias<4, 2>(acc1, d_b0 + wc * 64, lk);
  gemm<128, 4, 2, 128>(Bs, 256, dW0t + (size_t)(wc * 64) * 128, acc1, wr, lrow, lk);
  store_lds_pk<4, 2, true>(Aa, 512, wc * 64, acc1, wr, lrow, lk);   // mid0d
  __syncthreads();

  f32x4 acc3[2][2];
  init_bias<2, 2>(acc3, d_b2 + wc * 32, lk);
#pragma unroll
  for (int g = 0; g < 2; ++g) {
    f32x4 acc2[4][2];
    init_bias<4, 2>(acc2, d_b1 + g * 256 + wc * 64, lk);
    gemm<256, 4, 2, 256>(Aa, 512, dW1t + (size_t)(g * 256 + wc * 64) * 256, acc2, wr, lrow, lk);
    if (g) __syncthreads();                   // gemm3(g=0) readers of Bs done
    store_lds_pk<4, 2, true>(Bs, 512, wc * 64, acc2, wr, lrow, lk);  // mid1d half
    __syncthreads();
    gemm<256, 2, 2, 512>(Bs, 512, dW2t + (size_t)(wc * 32) * 512 + g * 256, acc3, wr, lrow, lk);
  }
  store_global<MODE, 2, 2>(gout, acc3, r0, wc * 32, wr, lrow, lk);
}

// ---- fused encoder + recon decoder --------------------------------------
// launch_bounds(512,4): hard 64-VGPR cap (hipcc: 131072/(512*4)=64); acc in
// AGPRs; total regs <=128 keeps 4 waves/SIMD (R11: occupancy 22->43%).
__launch_bounds__(512, 4)
__global__ void enc_dec_kernel(const float* __restrict__ in,
                               const unsigned short* __restrict__ eW0t, const float* __restrict__ e_b0,
                               const unsigned short* __restrict__ eW1t, const float* __restrict__ e_b1,
                               const unsigned short* __restrict__ eW2t, const float* __restrict__ e_b2,
                               const unsigned short* __restrict__ dW0t, const float* __restrict__ d_b0,
                               const unsigned short* __restrict__ dW1t, const float* __restrict__ d_b1,
                               const unsigned short* __restrict__ dW2t, const float* __restrict__ d_b2,
                               float* __restrict__ z, float* __restrict__ x_rec,
                               float* __restrict__ x_pred) {
  __shared__ __align__(16) char Aa[M_ * 512];   // 32KB arena
  __shared__ __align__(16) char Bs[M_ * 512];   // 32KB arena

  const int tid  = threadIdx.x;
  const int wave = tid >> 6;
  const int lane = tid & 63;
  const int lrow = lane & 15;
  const int lk   = lane >> 4;
  const int r0   = blockIdx.x * M_;
  const int wc   = wave & 3;
  const int wr   = (wave >> 2) * 32;

  stage<MODE_ENC>(in, Aa, x_pred, r0, tid);   // input @Aa stride 256 (16KB)
  __syncthreads();

  // encoder: 128 -> 512(relu, 2 halves) -> 256(relu) -> 128
  f32x4 acc2[4][2];
  init_bias<4, 2>(acc2, e_b1 + wc * 64, lk);
#pragma unroll
  for (int h = 0; h < 2; ++h) {
    f32x4 acc1[4][2];
    init_bias<4, 2>(acc1, e_b0 + h * 256 + wc * 64, lk);
    gemm<128, 4, 2, 128>(Aa, 256, eW0t + (size_t)(h * 256 + wc * 64) * 128, acc1, wr, lrow, lk);
    if (h) __syncthreads();                   // gemm2(h=0) readers of Bs done
    store_lds_pk<4, 2, true>(Bs, 512, wc * 64, acc1, wr, lrow, lk);  // a1 half
    __syncthreads();
    gemm<256, 4, 2, 512>(Bs, 512, eW1t + (size_t)(wc * 64) * 512 + h * 256, acc2, wr, lrow, lk);
  }
  // all waves past last bar (post-a1-store, pre-gemm2) -> done with Aa input
  store_lds_pk<4, 2, true>(Aa, 512, wc * 64, acc2, wr, lrow, lk);    // mid1 (256c)
  __syncthreads();                            // also: all waves past gemm2(h=1)

  f32x4 acc3[2][2];
  init_bias<2, 2>(acc3, e_b2 + wc * 32, lk);
  gemm<256, 2, 2, 256>(Aa, 512, eW2t + (size_t)(wc * 32) * 256, acc3, wr, lrow, lk);
  // Bs free (all waves past gemm2(h=1) via last bar): h_enc bf16 + z f32
  store_lds_pk<2, 2, false>(Bs, 256, wc * 32, acc3, wr, lrow, lk);
  store_global<MODE_ENC, 2, 2>(z, acc3, r0, wc * 32, wr, lrow, lk);
  __syncthreads();                            // h_enc visible; all past gemm3(Aa)

  dec_body<MODE_ID>(dW0t, d_b0, dW1t, d_b1, dW2t, d_b2, x_rec, Aa, Bs, r0, wave, lrow, lk);
}

// ---- pred decoder (after scan): decoder(tanh(z rows)) -> x_pred ----------
__launch_bounds__(512, 4)
__global__ void pred_dec_kernel(const float* __restrict__ zin,
                                const unsigned short* __restrict__ dW0t, const float* __restrict__ d_b0,
                                const unsigned short* __restrict__ dW1t, const float* __restrict__ d_b1,
                                const unsigned short* __restrict__ dW2t, const float* __restrict__ d_b2,
                                float* __restrict__ x_pred) {
  __shared__ __align__(16) char Aa[M_ * 512];
  __shared__ __align__(16) char Bs[M_ * 512];

  const int tid  = threadIdx.x;
  const int wave = tid >> 6;
  const int lane = tid & 63;
  const int lrow = lane & 15;
  const int lk   = lane >> 4;
  const int r0   = blockIdx.x * M_;

  stage<MODE_TANH>(zin, Bs, nullptr, r0, tid);   // input @Bs stride 256
  __syncthreads();
  dec_body<MODE_TANH>(dW0t, d_b0, dW1t, d_b1, dW2t, d_b2, x_pred, Aa, Bs, r0, wave, lrow, lk);
}

// ---- fused weight prep: all six fp32 [K][N] -> bf16 [N][K] ---------------
__global__ void wprep_all_kernel(const float* __restrict__ s0, const float* __restrict__ s1,
                                 const float* __restrict__ s2, const float* __restrict__ s3,
                                 const float* __restrict__ s4, const float* __restrict__ s5,
                                 unsigned short* __restrict__ d0, unsigned short* __restrict__ d1,
                                 unsigned short* __restrict__ d2, unsigned short* __restrict__ d3,
                                 unsigned short* __restrict__ d4, unsigned short* __restrict__ d5) {
  const int id = blockIdx.x * blockDim.x + threadIdx.x;
  const float* src; unsigned short* dst; int K, N, l;
  if (id < 65536)       { src = s0; dst = d0; K = 128; N = 512; l = id; }
  else if (id < 196608) { src = s1; dst = d1; K = 512; N = 256; l = id - 65536; }
  else if (id < 229376) { src = s2; dst = d2; K = 256; N = 128; l = id - 196608; }
  else if (id < 262144) { src = s3; dst = d3; K = 128; N = 256; l = id - 229376; }
  else if (id < 393216) { src = s4; dst = d4; K = 256; N = 512; l = id - 262144; }
  else                  { src = s5; dst = d5; K = 512; N = 128; l = id - 393216; }
  const int k = l / N;
  const int n = l - k * N;
  dst[(size_t)n * K + k] = f2bf(src[l]);
}

// ---- RNN scan (fp32, sequential, tiny) ----------------------------------
__global__ void rnn_scan_kernel(const float* __restrict__ noise,
                                const float* __restrict__ m, const float* __restrict__ n,
                                float* __restrict__ z) {
  const int gtid = blockIdx.x * blockDim.x + threadIdx.x;
  const int b = gtid >> 6;
  const int lane = threadIdx.x & 63;
  const int k0 = lane, k1 = lane + 64;

  const float mk00 = m[k0 * 2], mk01 = m[k0 * 2 + 1];
  const float mk10 = m[k1 * 2], mk11 = m[k1 * 2 + 1];
  const float nk00 = n[k0 * 2], nk01 = n[k0 * 2 + 1];
  const float nk10 = n[k1 * 2], nk11 = n[k1 * 2 + 1];

  float* zb = z + (size_t)b * T_ * D_;
  const float* nzb = noise + (size_t)b * (T_ - 1) * D_;
  float h0 = zb[k0];
  float h1 = zb[k1];

#pragma unroll 1
  for (int t = 0; t < T_ - 1; ++t) {
    const float r0v = tanhf(h0);
    const float r1v = tanhf(h1);
    float p0 = r0v * nk00 + r1v * nk10;
    float p1 = r0v * nk01 + r1v * nk11;
#pragma unroll
    for (int off = 32; off > 0; off >>= 1) {
      p0 += __shfl_xor(p0, off);
      p1 += __shfl_xor(p1, off);
    }
    const float v0 = (p0 * mk00 + p1 * mk01) * (1.0f / 128.0f);
    const float v1 = (p0 * mk10 + p1 * mk11) * (1.0f / 128.0f);
    const float nz0 = nzb[t * D_ + k0];
    const float nz1 = nzb[t * D_ + k1];
    h0 += 0.2f * (v0 - h0) + 0.05f * nz0;
    h1 += 0.2f * (v1 - h1) + 0.05f * nz1;
    zb[(t + 1) * D_ + k0] = h0;
    zb[(t + 1) * D_ + k1] = h1;
  }
}

}  // namespace

extern "C" void kernel_launch(void* const* d_in, const int* in_sizes, int n_in,
                              void* d_out, int out_size, void* d_ws, size_t ws_size,
                              hipStream_t stream) {
  (void)in_sizes; (void)n_in; (void)ws_size; (void)out_size;

  const float* x     = (const float*)d_in[0];
  const float* noise = (const float*)d_in[1];
  const float* e_w0 = (const float*)d_in[3];
  const float* e_b0 = (const float*)d_in[4];
  const float* e_w1 = (const float*)d_in[5];
  const float* e_b1 = (const float*)d_in[6];
  const float* e_w2 = (const float*)d_in[7];
  const float* e_b2 = (const float*)d_in[8];
  const float* d_w0 = (const float*)d_in[9];
  const float* d_b0 = (const float*)d_in[10];
  const float* d_w1 = (const float*)d_in[11];
  const float* d_b1 = (const float*)d_in[12];
  const float* d_w2 = (const float*)d_in[13];
  const float* d_b2 = (const float*)d_in[14];
  const float* m    = (const float*)d_in[15];
  const float* n    = (const float*)d_in[16];

  float* out    = (float*)d_out;
  float* x_pred = out;                          // (B,T,128)
  float* x_rec  = out + (size_t)BT_ * D_;       // (B,T,128)
  float* z      = out + 2 * (size_t)BT_ * D_;   // (B,T,128)

  unsigned short* ws = (unsigned short*)d_ws;
  unsigned short* eW0t = ws;            // 512x128
  unsigned short* eW1t = ws + 65536;    // 256x512
  unsigned short* eW2t = ws + 196608;   // 128x256
  unsigned short* dW0t = ws + 229376;   // 256x128
  unsigned short* dW1t = ws + 262144;   // 512x256
  unsigned short* dW2t = ws + 393216;   // 128x512

  wprep_all_kernel<<<458752 / 256, 256, 0, stream>>>(e_w0, e_w1, e_w2, d_w0, d_w1, d_w2,
                                                     eW0t, eW1t, eW2t, dW0t, dW1t, dW2t);

  // 1) fused encoder + recon decoder: x -> h_enc (z region) + x_reconstruct
  //    (side-writes x_pred[:,0,:] = cleaned x0)
  enc_dec_kernel<<<BT_ / M_, 512, 0, stream>>>(x,
      eW0t, e_b0, eW1t, e_b1, eW2t, e_b2,
      dW0t, d_b0, dW1t, d_b1, dW2t, d_b2,
      z, x_rec, x_pred);

  // 2) RNN scan: z[:,1:,:] = h_1..h_99 (z[:,0,:] already h0)
  rnn_scan_kernel<<<B_ / 4, 256, 0, stream>>>(noise, m, n, z);

  // 3) pred decoder: decoder(tanh(z[:,1:,:])) -> x_pred[:,1:,:]
  pred_dec_kernel<<<(B_ * (T_ - 1)) / M_, 512, 0, stream>>>(z,
      dW0t, d_b0, dW1t, d_b1, dW2t, d_b2, x_pred);
}

// Round 14
// 676.736 us; speedup vs baseline: 1.7041x; 1.7041x over previous
//
#include <hip/hip_runtime.h>
#include <math.h>

namespace {

constexpr int B_  = 2048;
constexpr int T_  = 100;
constexpr int D_  = 128;
constexpr int BT_ = B_ * T_;     // 204800
constexpr int M_  = 64;          // rows per block

using f32x4  = __attribute__((ext_vector_type(4))) float;
using bf16x8 = __attribute__((ext_vector_type(8))) __bf16;

enum { MODE_ENC = 0, MODE_ID = 1, MODE_TANH = 2 };

// Manual RNE f32->bf16. R9 lesson: v_cvt_pk_bf16_f32 is NOT round-nearest-even
// here (absmax 0.002 -> 0.091, within 9% of the fail threshold). Keep manual.
__device__ __forceinline__ unsigned short f2bf(float f) {
  unsigned int u = __float_as_uint(f);
  return (unsigned short)((u + 0x7FFFu + ((u >> 16) & 1u)) >> 16);
}
__device__ __forceinline__ unsigned int pack2(float a, float b) {
  return (unsigned int)f2bf(a) | ((unsigned int)f2bf(b) << 16);
}
__device__ __forceinline__ float ftanh(float x) {   // feeds bf16; err ~1e-6 << bf16 ulp
  const float e = __expf(2.0f * x);
  return 1.0f - 2.0f / (e + 1.0f);
}

// ---- swapped-operand MFMA GEMM (R11 geometry: NT col-tiles x 4 subtiles) --
// out[r][c] = sum_k act[r][k] * W[c][k] via mfma(A-op=W, B-op=act):
// D col(lane&15)=act-row, D row(lk*4+j)=W-col -> lane holds 4 CONSECUTIVE
// N-cols of one act row. A: 64 rows bf16 in LDS, stride astr, 16B slots
// XOR-swizzled by ((row&15)<<4) (write/read apply the same XOR -> consistent).
// Wt: bf16 [col][KFW] pre-offset to wave col0. acc[nt][s]: col-tile nt,
// act-rows s*16..+16. R13 lesson: keep per-wave W footprint at 32 cols
// (L1-resident); R12 lesson: keep acc as f32x4 arrays (AGPR-friendly).
template <int KGEMM, int NT, int KFW>
__device__ __forceinline__ void gemm(const char* __restrict__ A, const int astr,
                                     const unsigned short* __restrict__ Wt,
                                     f32x4 (&acc)[NT][4], const int lrow, const int lk) {
  constexpr int NK = KGEMM / 32;
  const int key = lrow << 4;
  const unsigned short* wl = Wt + lk * 8;        // lane's k-phase
#pragma unroll
  for (int kk = 0; kk < NK; ++kk) {
    int4 breg[NT];
#pragma unroll
    for (int nt = 0; nt < NT; ++nt)
      breg[nt] = *reinterpret_cast<const int4*>(
          wl + (size_t)(nt * 16 + lrow) * KFW + kk * 32);
    bf16x8 act[4];
#pragma unroll
    for (int s = 0; s < 4; ++s)
      act[s] = __builtin_bit_cast(bf16x8,
          *reinterpret_cast<const int4*>(A + (s * 16 + lrow) * astr + ((kk * 64 + lk * 16) ^ key)));
#pragma unroll
    for (int nt = 0; nt < NT; ++nt) {
      const bf16x8 w = __builtin_bit_cast(bf16x8, breg[nt]);
#pragma unroll
      for (int s = 0; s < 4; ++s)
        acc[nt][s] = __builtin_amdgcn_mfma_f32_16x16x32_bf16(w, act[s], acc[nt][s], 0, 0, 0);
    }
  }
}

// bias[col]: lane's 4 acc elems are 4 consecutive cols -> float4 load.
template <int NT>
__device__ __forceinline__ void init_bias(f32x4 (&acc)[NT][4], const float* __restrict__ bias,
                                          const int lk) {
#pragma unroll
  for (int nt = 0; nt < NT; ++nt) {
    const f32x4 bv = *reinterpret_cast<const f32x4*>(bias + nt * 16 + lk * 4);
#pragma unroll
    for (int s = 0; s < 4; ++s) acc[nt][s] = bv;
  }
}

// (relu?) + RNE bf16 pack + 8B LDS store (row stride strideB, swizzled).
template <int NT, bool RELU>
__device__ __forceinline__ void store_lds_pk(char* __restrict__ dst, const int strideB,
                                             const int colLocal0, f32x4 (&acc)[NT][4],
                                             const int lrow, const int lk) {
  const int key = lrow << 4;
#pragma unroll
  for (int nt = 0; nt < NT; ++nt) {
    const int colb = (colLocal0 + nt * 16 + lk * 4) * 2;
#pragma unroll
    for (int s = 0; s < 4; ++s) {
      float v0 = acc[nt][s][0], v1 = acc[nt][s][1], v2 = acc[nt][s][2], v3 = acc[nt][s][3];
      if (RELU) {
        v0 = fmaxf(v0, 0.f); v1 = fmaxf(v1, 0.f); v2 = fmaxf(v2, 0.f); v3 = fmaxf(v3, 0.f);
      }
      uint2 w;
      w.x = pack2(v0, v1);
      w.y = pack2(v2, v3);
      *reinterpret_cast<uint2*>(dst + (s * 16 + lrow) * strideB + (colb ^ key)) = w;
    }
  }
}

template <int MODE>
__device__ __forceinline__ int rowmap(const int rl) {
  if constexpr (MODE == MODE_TANH) {
    const int b = rl / 99;
    return b * T_ + (rl - b * 99) + 1;
  }
  return rl;
}

// final layer: lane's 4 cols contiguous -> direct float4 global store.
template <int MODE>
__device__ __forceinline__ void store_global(float* __restrict__ gout, f32x4 (&acc)[1][4],
                                             const int r0, const int col0,
                                             const int lrow, const int lk) {
#pragma unroll
  for (int s = 0; s < 4; ++s) {
    const int g = rowmap<MODE>(r0 + s * 16 + lrow);
    *reinterpret_cast<float4*>(gout + (size_t)g * D_ + col0 + lk * 4) =
        __builtin_bit_cast(float4, acc[0][s]);
  }
}

// stage 64 rows x 128 f32 -> bf16 LDS (stride 256B, swizzled); 512 threads.
template <int MODE>
__device__ __forceinline__ void stage(const float* __restrict__ in, char* __restrict__ X,
                                      float* __restrict__ xpred0,
                                      const int r0, const int tid) {
#pragma unroll
  for (int i = 0; i < 2; ++i) {
    const int c   = tid + i * 512;   // 1024 chunks of 8 floats
    const int row = c >> 4;
    const int cb  = c & 15;
    const int rl  = r0 + row;
    const int g   = rowmap<MODE>(rl);
    const float4* gp = reinterpret_cast<const float4*>(in + (size_t)g * D_ + cb * 8);
    float4 v0 = gp[0], v1 = gp[1];
    if constexpr (MODE == MODE_ENC) {
      v0.x = (v0.x == v0.x) ? v0.x : 0.f;  v0.y = (v0.y == v0.y) ? v0.y : 0.f;
      v0.z = (v0.z == v0.z) ? v0.z : 0.f;  v0.w = (v0.w == v0.w) ? v0.w : 0.f;
      v1.x = (v1.x == v1.x) ? v1.x : 0.f;  v1.y = (v1.y == v1.y) ? v1.y : 0.f;
      v1.z = (v1.z == v1.z) ? v1.z : 0.f;  v1.w = (v1.w == v1.w) ? v1.w : 0.f;
      if (rl % T_ == 0) {   // x_pred[:,0,:] = cleaned x[:,0,:]
        float4* xp = reinterpret_cast<float4*>(xpred0 + (size_t)g * D_ + cb * 8);
        xp[0] = v0; xp[1] = v1;
      }
    }
    if constexpr (MODE == MODE_TANH) {
      v0.x = ftanh(v0.x); v0.y = ftanh(v0.y); v0.z = ftanh(v0.z); v0.w = ftanh(v0.w);
      v1.x = ftanh(v1.x); v1.y = ftanh(v1.y); v1.z = ftanh(v1.z); v1.w = ftanh(v1.w);
    }
    int4 pk;
    pk.x = (int)pack2(v0.x, v0.y); pk.y = (int)pack2(v0.z, v0.w);
    pk.z = (int)pack2(v1.x, v1.y); pk.w = (int)pack2(v1.z, v1.w);
    *reinterpret_cast<int4*>(X + row * 256 + ((cb * 16) ^ ((row & 15) << 4))) = pk;
  }
}

// ---- decoder body: input bf16 in X (stride 256) -> gout rows rowmap ------
// 128 -> 256(relu -> Ylo str512) -> 512(relu, halves -> Yhi str512) -> 128.
// Entry condition: all waves past a barrier after their last X/Y use.
template <int MODE>
__device__ __forceinline__ void dec_body(const unsigned short* __restrict__ dW0t, const float* __restrict__ d_b0,
                                         const unsigned short* __restrict__ dW1t, const float* __restrict__ d_b1,
                                         const unsigned short* __restrict__ dW2t, const float* __restrict__ d_b2,
                                         float* __restrict__ gout,
                                         char* __restrict__ X, char* __restrict__ Y,
                                         const int r0, const int wave, const int lrow, const int lk) {
  char* Yhi = Y + 32768;

  f32x4 acc1[2][4];
  init_bias<2>(acc1, d_b0 + wave * 32, lk);
  gemm<128, 2, 128>(X, 256, dW0t + (size_t)(wave * 32) * 128, acc1, lrow, lk);
  store_lds_pk<2, true>(Y, 512, wave * 32, acc1, lrow, lk);   // mid0d -> Y[0:32K]
  __syncthreads();

  f32x4 acc3[1][4];
  init_bias<1>(acc3, d_b2 + wave * 16, lk);
#pragma unroll
  for (int g = 0; g < 2; ++g) {
    f32x4 acc2[2][4];
    init_bias<2>(acc2, d_b1 + g * 256 + wave * 32, lk);
    gemm<256, 2, 256>(Y, 512, dW1t + (size_t)(g * 256 + wave * 32) * 256, acc2, lrow, lk);
    if (g) __syncthreads();                   // gemm3(g=0) readers of Yhi done
    store_lds_pk<2, true>(Yhi, 512, wave * 32, acc2, lrow, lk);  // mid1d half
    __syncthreads();
    gemm<256, 1, 512>(Yhi, 512, dW2t + (size_t)(wave * 16) * 512 + g * 256, acc3, lrow, lk);
  }
  store_global<MODE>(gout, acc3, r0, wave * 16, lrow, lk);
}

// ---- fused encoder + recon decoder --------------------------------------
// launch_bounds(512,4): hard 64-VGPR cap; acc in AGPRs. R14: Y=64KB holds
// the FULL a1 (str 1024), so gemm2 runs once with K=512 and at most ONE
// 32-AGPR acc set is live anywhere -> no spill pressure under the cap.
// LDS 80KB -> still 2 blocks/CU (160KB). Barriers 11 -> 9.
__launch_bounds__(512, 4)
__global__ void enc_dec_kernel(const float* __restrict__ in,
                               const unsigned short* __restrict__ eW0t, const float* __restrict__ e_b0,
                               const unsigned short* __restrict__ eW1t, const float* __restrict__ e_b1,
                               const unsigned short* __restrict__ eW2t, const float* __restrict__ e_b2,
                               const unsigned short* __restrict__ dW0t, const float* __restrict__ d_b0,
                               const unsigned short* __restrict__ dW1t, const float* __restrict__ d_b1,
                               const unsigned short* __restrict__ dW2t, const float* __restrict__ d_b2,
                               float* __restrict__ z, float* __restrict__ x_rec,
                               float* __restrict__ x_pred) {
  __shared__ __align__(16) char X[M_ * 256];    // 16KB: input, later h_enc
  __shared__ __align__(16) char Y[M_ * 1024];   // 64KB: a1 full / mid1 / dec arenas

  const int tid  = threadIdx.x;
  const int wave = tid >> 6;
  const int lane = tid & 63;
  const int lrow = lane & 15;
  const int lk   = lane >> 4;
  const int r0   = blockIdx.x * M_;

  stage<MODE_ENC>(in, X, x_pred, r0, tid);   // input @X str 256
  __syncthreads();                                            // bar1

  // enc L1: 128 -> 512(relu), both halves -> Y str 1024 (disjoint bytes)
#pragma unroll
  for (int h = 0; h < 2; ++h) {
    f32x4 acc1[2][4];
    init_bias<2>(acc1, e_b0 + h * 256 + wave * 32, lk);
    gemm<128, 2, 128>(X, 256, eW0t + (size_t)(h * 256 + wave * 32) * 128, acc1, lrow, lk);
    store_lds_pk<2, true>(Y, 1024, h * 256 + wave * 32, acc1, lrow, lk);
  }
  __syncthreads();                                            // bar2: a1 complete

  // enc L2: K=512 in one pass (single live acc set)
  f32x4 acc2[2][4];
  init_bias<2>(acc2, e_b1 + wave * 32, lk);
  gemm<512, 2, 512>(Y, 1024, eW1t + (size_t)(wave * 32) * 512, acc2, lrow, lk);
  __syncthreads();                                            // bar3: Y readers done
  store_lds_pk<2, true>(Y, 512, wave * 32, acc2, lrow, lk);   // mid1 -> Y[0:32K]
  __syncthreads();                                            // bar4

  // enc L3: 256 -> 128; h_enc -> X (input dead since bar2), z -> global
  f32x4 acc3[1][4];
  init_bias<1>(acc3, e_b2 + wave * 16, lk);
  gemm<256, 1, 256>(Y, 512, eW2t + (size_t)(wave * 16) * 256, acc3, lrow, lk);
  store_lds_pk<1, false>(X, 256, wave * 16, acc3, lrow, lk);
  store_global<MODE_ENC>(z, acc3, r0, wave * 16, lrow, lk);
  __syncthreads();                                            // bar5

  dec_body<MODE_ID>(dW0t, d_b0, dW1t, d_b1, dW2t, d_b2, x_rec, X, Y, r0, wave, lrow, lk);
}

// ---- pred decoder (after scan): decoder(tanh(z rows)) -> x_pred ----------
__launch_bounds__(512, 4)
__global__ void pred_dec_kernel(const float* __restrict__ zin,
                                const unsigned short* __restrict__ dW0t, const float* __restrict__ d_b0,
                                const unsigned short* __restrict__ dW1t, const float* __restrict__ d_b1,
                                const unsigned short* __restrict__ dW2t, const float* __restrict__ d_b2,
                                float* __restrict__ x_pred) {
  __shared__ __align__(16) char X[M_ * 256];
  __shared__ __align__(16) char Y[M_ * 1024];

  const int tid  = threadIdx.x;
  const int wave = tid >> 6;
  const int lane = tid & 63;
  const int lrow = lane & 15;
  const int lk   = lane >> 4;
  const int r0   = blockIdx.x * M_;

  stage<MODE_TANH>(zin, X, nullptr, r0, tid);   // input @X str 256
  __syncthreads();
  dec_body<MODE_TANH>(dW0t, d_b0, dW1t, d_b1, dW2t, d_b2, x_pred, X, Y, r0, wave, lrow, lk);
}

// ---- fused weight prep: all six fp32 [K][N] -> bf16 [N][K] ---------------
__global__ void wprep_all_kernel(const float* __restrict__ s0, const float* __restrict__ s1,
                                 const float* __restrict__ s2, const float* __restrict__ s3,
                                 const float* __restrict__ s4, const float* __restrict__ s5,
                                 unsigned short* __restrict__ d0, unsigned short* __restrict__ d1,
                                 unsigned short* __restrict__ d2, unsigned short* __restrict__ d3,
                                 unsigned short* __restrict__ d4, unsigned short* __restrict__ d5) {
  const int id = blockIdx.x * blockDim.x + threadIdx.x;
  const float* src; unsigned short* dst; int K, N, l;
  if (id < 65536)       { src = s0; dst = d0; K = 128; N = 512; l = id; }
  else if (id < 196608) { src = s1; dst = d1; K = 512; N = 256; l = id - 65536; }
  else if (id < 229376) { src = s2; dst = d2; K = 256; N = 128; l = id - 196608; }
  else if (id < 262144) { src = s3; dst = d3; K = 128; N = 256; l = id - 229376; }
  else if (id < 393216) { src = s4; dst = d4; K = 256; N = 512; l = id - 262144; }
  else                  { src = s5; dst = d5; K = 512; N = 128; l = id - 393216; }
  const int k = l / N;
  const int n = l - k * N;
  dst[(size_t)n * K + k] = f2bf(src[l]);
}

// ---- RNN scan (fp32, sequential, tiny) ----------------------------------
__global__ void rnn_scan_kernel(const float* __restrict__ noise,
                                const float* __restrict__ m, const float* __restrict__ n,
                                float* __restrict__ z) {
  const int gtid = blockIdx.x * blockDim.x + threadIdx.x;
  const int b = gtid >> 6;
  const int lane = threadIdx.x & 63;
  const int k0 = lane, k1 = lane + 64;

  const float mk00 = m[k0 * 2], mk01 = m[k0 * 2 + 1];
  const float mk10 = m[k1 * 2], mk11 = m[k1 * 2 + 1];
  const float nk00 = n[k0 * 2], nk01 = n[k0 * 2 + 1];
  const float nk10 = n[k1 * 2], nk11 = n[k1 * 2 + 1];

  float* zb = z + (size_t)b * T_ * D_;
  const float* nzb = noise + (size_t)b * (T_ - 1) * D_;
  float h0 = zb[k0];
  float h1 = zb[k1];

#pragma unroll 1
  for (int t = 0; t < T_ - 1; ++t) {
    const float r0v = tanhf(h0);
    const float r1v = tanhf(h1);
    float p0 = r0v * nk00 + r1v * nk10;
    float p1 = r0v * nk01 + r1v * nk11;
#pragma unroll
    for (int off = 32; off > 0; off >>= 1) {
      p0 += __shfl_xor(p0, off);
      p1 += __shfl_xor(p1, off);
    }
    const float v0 = (p0 * mk00 + p1 * mk01) * (1.0f / 128.0f);
    const float v1 = (p0 * mk10 + p1 * mk11) * (1.0f / 128.0f);
    const float nz0 = nzb[t * D_ + k0];
    const float nz1 = nzb[t * D_ + k1];
    h0 += 0.2f * (v0 - h0) + 0.05f * nz0;
    h1 += 0.2f * (v1 - h1) + 0.05f * nz1;
    zb[(t + 1) * D_ + k0] = h0;
    zb[(t + 1) * D_ + k1] = h1;
  }
}

}  // namespace

extern "C" void kernel_launch(void* const* d_in, const int* in_sizes, int n_in,
                              void* d_out, int out_size, void* d_ws, size_t ws_size,
                              hipStream_t stream) {
  (void)in_sizes; (void)n_in; (void)ws_size; (void)out_size;

  const float* x     = (const float*)d_in[0];
  const float* noise = (const float*)d_in[1];
  const float* e_w0 = (const float*)d_in[3];
  const float* e_b0 = (const float*)d_in[4];
  const float* e_w1 = (const float*)d_in[5];
  const float* e_b1 = (const float*)d_in[6];
  const float* e_w2 = (const float*)d_in[7];
  const float* e_b2 = (const float*)d_in[8];
  const float* d_w0 = (const float*)d_in[9];
  const float* d_b0 = (const float*)d_in[10];
  const float* d_w1 = (const float*)d_in[11];
  const float* d_b1 = (const float*)d_in[12];
  const float* d_w2 = (const float*)d_in[13];
  const float* d_b2 = (const float*)d_in[14];
  const float* m    = (const float*)d_in[15];
  const float* n    = (const float*)d_in[16];

  float* out    = (float*)d_out;
  float* x_pred = out;                          // (B,T,128)
  float* x_rec  = out + (size_t)BT_ * D_;       // (B,T,128)
  float* z      = out + 2 * (size_t)BT_ * D_;   // (B,T,128)

  unsigned short* ws = (unsigned short*)d_ws;
  unsigned short* eW0t = ws;            // 512x128
  unsigned short* eW1t = ws + 65536;    // 256x512
  unsigned short* eW2t = ws + 196608;   // 128x256
  unsigned short* dW0t = ws + 229376;   // 256x128
  unsigned short* dW1t = ws + 262144;   // 512x256
  unsigned short* dW2t = ws + 393216;   // 128x512

  wprep_all_kernel<<<458752 / 256, 256, 0, stream>>>(e_w0, e_w1, e_w2, d_w0, d_w1, d_w2,
                                                     eW0t, eW1t, eW2t, dW0t, dW1t, dW2t);

  // 1) fused encoder + recon decoder: x -> h_enc (z region) + x_reconstruct
  //    (side-writes x_pred[:,0,:] = cleaned x0)
  enc_dec_kernel<<<BT_ / M_, 512, 0, stream>>>(x,
      eW0t, e_b0, eW1t, e_b1, eW2t, e_b2,
      dW0t, d_b0, dW1t, d_b1, dW2t, d_b2,
      z, x_rec, x_pred);

  // 2) RNN scan: z[:,1:,:] = h_1..h_99 (z[:,0,:] already h0)
  rnn_scan_kernel<<<B_ / 4, 256, 0, stream>>>(noise, m, n, z);

  // 3) pred decoder: decoder(tanh(z[:,1:,:])) -> x_pred[:,1:,:]
  pred_dec_kernel<<<(B_ * (T_ - 1)) / M_, 512, 0, stream>>>(z,
      dW0t, d_b0, dW1t, d_b1, dW2t, d_b2, x_pred);
}

// Round 15
// 664.525 us; speedup vs baseline: 1.7355x; 1.0184x over previous
//
#include <hip/hip_runtime.h>
#include <math.h>

namespace {

constexpr int B_  = 2048;
constexpr int T_  = 100;
constexpr int D_  = 128;
constexpr int BT_ = B_ * T_;     // 204800
constexpr int M_  = 64;          // rows per block

using f32x4  = __attribute__((ext_vector_type(4))) float;
using bf16x8 = __attribute__((ext_vector_type(8))) __bf16;

enum { MODE_ENC = 0, MODE_ID = 1, MODE_TANH = 2 };

// Manual RNE f32->bf16. R9 lesson: v_cvt_pk_bf16_f32 is NOT round-nearest-even
// here (absmax 0.002 -> 0.091). Keep manual.
__device__ __forceinline__ unsigned short f2bf(float f) {
  unsigned int u = __float_as_uint(f);
  return (unsigned short)((u + 0x7FFFu + ((u >> 16) & 1u)) >> 16);
}
__device__ __forceinline__ unsigned int pack2(float a, float b) {
  return (unsigned int)f2bf(a) | ((unsigned int)f2bf(b) << 16);
}
__device__ __forceinline__ float ftanh(float x) {   // feeds bf16; err ~1e-6 << bf16 ulp
  const float e = __expf(2.0f * x);
  return 1.0f - 2.0f / (e + 1.0f);
}

// ---- swapped-operand MFMA GEMM (R11 geometry: NT col-tiles x 4 subtiles) --
// out[r][c] = sum_k act[r][k] * W[c][k] via mfma(A-op=W, B-op=act):
// D col(lane&15)=act-row, D row(lk*4+j)=W-col -> lane holds 4 CONSECUTIVE
// N-cols of one act row. A: 64 rows bf16 in LDS, stride astr, 16B slots
// XOR-swizzled by ((row&15)<<4). Wt: bf16 [col][KFW] pre-offset to wave col0.
// R13 lesson: keep per-wave W slice <=32 cols; R12 lesson: f32x4 acc only.
template <int KGEMM, int NT, int KFW>
__device__ __forceinline__ void gemm(const char* __restrict__ A, const int astr,
                                     const unsigned short* __restrict__ Wt,
                                     f32x4 (&acc)[NT][4], const int lrow, const int lk) {
  constexpr int NK = KGEMM / 32;
  const int key = lrow << 4;
  const unsigned short* wl = Wt + lk * 8;        // lane's k-phase
#pragma unroll
  for (int kk = 0; kk < NK; ++kk) {
    int4 breg[NT];
#pragma unroll
    for (int nt = 0; nt < NT; ++nt)
      breg[nt] = *reinterpret_cast<const int4*>(
          wl + (size_t)(nt * 16 + lrow) * KFW + kk * 32);
    bf16x8 act[4];
#pragma unroll
    for (int s = 0; s < 4; ++s)
      act[s] = __builtin_bit_cast(bf16x8,
          *reinterpret_cast<const int4*>(A + (s * 16 + lrow) * astr + ((kk * 64 + lk * 16) ^ key)));
#pragma unroll
    for (int nt = 0; nt < NT; ++nt) {
      const bf16x8 w = __builtin_bit_cast(bf16x8, breg[nt]);
#pragma unroll
      for (int s = 0; s < 4; ++s)
        acc[nt][s] = __builtin_amdgcn_mfma_f32_16x16x32_bf16(w, act[s], acc[nt][s], 0, 0, 0);
    }
  }
}

// bias[col]: lane's 4 acc elems are 4 consecutive cols -> float4 load.
template <int NT>
__device__ __forceinline__ void init_bias(f32x4 (&acc)[NT][4], const float* __restrict__ bias,
                                          const int lk) {
#pragma unroll
  for (int nt = 0; nt < NT; ++nt) {
    const f32x4 bv = *reinterpret_cast<const f32x4*>(bias + nt * 16 + lk * 4);
#pragma unroll
    for (int s = 0; s < 4; ++s) acc[nt][s] = bv;
  }
}

// (relu?) + RNE bf16 pack + 8B LDS store (row stride strideB, swizzled).
template <int NT, bool RELU>
__device__ __forceinline__ void store_lds_pk(char* __restrict__ dst, const int strideB,
                                             const int colLocal0, f32x4 (&acc)[NT][4],
                                             const int lrow, const int lk) {
  const int key = lrow << 4;
#pragma unroll
  for (int nt = 0; nt < NT; ++nt) {
    const int colb = (colLocal0 + nt * 16 + lk * 4) * 2;
#pragma unroll
    for (int s = 0; s < 4; ++s) {
      float v0 = acc[nt][s][0], v1 = acc[nt][s][1], v2 = acc[nt][s][2], v3 = acc[nt][s][3];
      if (RELU) {
        v0 = fmaxf(v0, 0.f); v1 = fmaxf(v1, 0.f); v2 = fmaxf(v2, 0.f); v3 = fmaxf(v3, 0.f);
      }
      uint2 w;
      w.x = pack2(v0, v1);
      w.y = pack2(v2, v3);
      *reinterpret_cast<uint2*>(dst + (s * 16 + lrow) * strideB + (colb ^ key)) = w;
    }
  }
}

template <int MODE>
__device__ __forceinline__ int rowmap(const int rl) {
  if constexpr (MODE == MODE_TANH) {
    const int b = rl / 99;
    return b * T_ + (rl - b * 99) + 1;
  }
  return rl;
}

// final layer: lane's 4 cols contiguous -> direct float4 global store.
template <int MODE>
__device__ __forceinline__ void store_global(float* __restrict__ gout, f32x4 (&acc)[1][4],
                                             const int r0, const int col0,
                                             const int lrow, const int lk) {
#pragma unroll
  for (int s = 0; s < 4; ++s) {
    const int g = rowmap<MODE>(r0 + s * 16 + lrow);
    *reinterpret_cast<float4*>(gout + (size_t)g * D_ + col0 + lk * 4) =
        __builtin_bit_cast(float4, acc[0][s]);
  }
}

// stage 64 rows x 128 f32 -> bf16 LDS (stride 256B, swizzled); 512 threads.
template <int MODE>
__device__ __forceinline__ void stage(const float* __restrict__ in, char* __restrict__ X,
                                      float* __restrict__ xpred0,
                                      const int r0, const int tid) {
#pragma unroll
  for (int i = 0; i < 2; ++i) {
    const int c   = tid + i * 512;   // 1024 chunks of 8 floats
    const int row = c >> 4;
    const int cb  = c & 15;
    const int rl  = r0 + row;
    const int g   = rowmap<MODE>(rl);
    const float4* gp = reinterpret_cast<const float4*>(in + (size_t)g * D_ + cb * 8);
    float4 v0 = gp[0], v1 = gp[1];
    if constexpr (MODE == MODE_ENC) {
      v0.x = (v0.x == v0.x) ? v0.x : 0.f;  v0.y = (v0.y == v0.y) ? v0.y : 0.f;
      v0.z = (v0.z == v0.z) ? v0.z : 0.f;  v0.w = (v0.w == v0.w) ? v0.w : 0.f;
      v1.x = (v1.x == v1.x) ? v1.x : 0.f;  v1.y = (v1.y == v1.y) ? v1.y : 0.f;
      v1.z = (v1.z == v1.z) ? v1.z : 0.f;  v1.w = (v1.w == v1.w) ? v1.w : 0.f;
      if (rl % T_ == 0) {   // x_pred[:,0,:] = cleaned x[:,0,:]
        float4* xp = reinterpret_cast<float4*>(xpred0 + (size_t)g * D_ + cb * 8);
        xp[0] = v0; xp[1] = v1;
      }
    }
    if constexpr (MODE == MODE_TANH) {
      v0.x = ftanh(v0.x); v0.y = ftanh(v0.y); v0.z = ftanh(v0.z); v0.w = ftanh(v0.w);
      v1.x = ftanh(v1.x); v1.y = ftanh(v1.y); v1.z = ftanh(v1.z); v1.w = ftanh(v1.w);
    }
    int4 pk;
    pk.x = (int)pack2(v0.x, v0.y); pk.y = (int)pack2(v0.z, v0.w);
    pk.z = (int)pack2(v1.x, v1.y); pk.w = (int)pack2(v1.z, v1.w);
    *reinterpret_cast<int4*>(X + row * 256 + ((cb * 16) ^ ((row & 15) << 4))) = pk;
  }
}

// ---- decoder body: input bf16 in X (str 256) -> gout rows rowmap ---------
// 128 -> 256(relu -> Y str512) -> 512(relu, 4 col-quarters bounced via X)
// -> 128 (K-accumulated over quarters).
// Entry: all waves past a barrier after their last X/Y use.
template <int MODE>
__device__ __forceinline__ void dec_body(const unsigned short* __restrict__ dW0t, const float* __restrict__ d_b0,
                                         const unsigned short* __restrict__ dW1t, const float* __restrict__ d_b1,
                                         const unsigned short* __restrict__ dW2t, const float* __restrict__ d_b2,
                                         float* __restrict__ gout,
                                         char* __restrict__ X, char* __restrict__ Y,
                                         const int r0, const int wave, const int lrow, const int lk) {
  f32x4 acc1[2][4];
  init_bias<2>(acc1, d_b0 + wave * 32, lk);
  gemm<128, 2, 128>(X, 256, dW0t + (size_t)(wave * 32) * 128, acc1, lrow, lk);
  store_lds_pk<2, true>(Y, 512, wave * 32, acc1, lrow, lk);   // mid0d -> Y
  __syncthreads();                          // also: all waves done reading X

  f32x4 acc3[1][4];
  init_bias<1>(acc3, d_b2 + wave * 16, lk);
#pragma unroll
  for (int q = 0; q < 4; ++q) {             // mid1d col-quarters (128 cols)
    f32x4 acc2[1][4];
    init_bias<1>(acc2, d_b1 + q * 128 + wave * 16, lk);
    gemm<256, 1, 256>(Y, 512, dW1t + (size_t)(q * 128 + wave * 16) * 256, acc2, lrow, lk);
    if (q) __syncthreads();                 // gemm3(q-1) readers of X done
    store_lds_pk<1, true>(X, 256, wave * 16, acc2, lrow, lk);
    __syncthreads();
    gemm<128, 1, 512>(X, 256, dW2t + (size_t)(wave * 16) * 512 + q * 128, acc3, lrow, lk);
  }
  store_global<MODE>(gout, acc3, r0, wave * 16, lrow, lk);
}

// ---- fused encoder + recon decoder --------------------------------------
// launch_bounds(512,4): hard 64-VGPR cap; acc in AGPRs (R11: restored
// 2-blocks/CU). R15: LDS 48KB (X 16K + Y 32K) -> 3 blocks/CU (24 waves,
// 75% cap). 256-col intermediates processed in halves/quarters via X.
__launch_bounds__(512, 4)
__global__ void enc_dec_kernel(const float* __restrict__ in,
                               const unsigned short* __restrict__ eW0t, const float* __restrict__ e_b0,
                               const unsigned short* __restrict__ eW1t, const float* __restrict__ e_b1,
                               const unsigned short* __restrict__ eW2t, const float* __restrict__ e_b2,
                               const unsigned short* __restrict__ dW0t, const float* __restrict__ d_b0,
                               const unsigned short* __restrict__ dW1t, const float* __restrict__ d_b1,
                               const unsigned short* __restrict__ dW2t, const float* __restrict__ d_b2,
                               float* __restrict__ z, float* __restrict__ x_rec,
                               float* __restrict__ x_pred) {
  __shared__ __align__(16) char X[M_ * 256];   // 16KB
  __shared__ __align__(16) char Y[M_ * 512];   // 32KB

  const int tid  = threadIdx.x;
  const int wave = tid >> 6;
  const int lane = tid & 63;
  const int lrow = lane & 15;
  const int lk   = lane >> 4;
  const int r0   = blockIdx.x * M_;

  stage<MODE_ENC>(in, X, x_pred, r0, tid);   // input @X str 256
  __syncthreads();

  // enc L1+L2 (R11 form): a1 halves -> Y; gemm2 accumulates K=512 over halves
  f32x4 acc2[2][4];
  init_bias<2>(acc2, e_b1 + wave * 32, lk);
#pragma unroll
  for (int h = 0; h < 2; ++h) {
    f32x4 acc1[2][4];
    init_bias<2>(acc1, e_b0 + h * 256 + wave * 32, lk);
    gemm<128, 2, 128>(X, 256, eW0t + (size_t)(h * 256 + wave * 32) * 128, acc1, lrow, lk);
    if (h) __syncthreads();                 // gemm2(h=0) readers of Y done
    store_lds_pk<2, true>(Y, 512, wave * 32, acc1, lrow, lk);
    __syncthreads();
    gemm<256, 2, 512>(Y, 512, eW1t + (size_t)(wave * 32) * 512 + h * 256, acc2, lrow, lk);
  }
  __syncthreads();                          // last gemm2 Y-reads + X-input dead

  // enc L3: mid1 (256 cols) in col-halves via X; K accumulated per half
  f32x4 acc3[1][4];
  init_bias<1>(acc3, e_b2 + wave * 16, lk);
#pragma unroll
  for (int hh = 0; hh < 2; ++hh) {
    if ((wave >> 2) == hh)                  // waves holding cols hh*128..+128
      store_lds_pk<2, true>(X, 256, (wave & 3) * 32, acc2, lrow, lk);
    __syncthreads();
    gemm<128, 1, 256>(X, 256, eW2t + (size_t)(wave * 16) * 256 + hh * 128, acc3, lrow, lk);
    __syncthreads();                        // X readers done before next store
  }
  store_lds_pk<1, false>(X, 256, wave * 16, acc3, lrow, lk);   // h_enc -> X
  store_global<MODE_ENC>(z, acc3, r0, wave * 16, lrow, lk);
  __syncthreads();                          // h_enc visible

  dec_body<MODE_ID>(dW0t, d_b0, dW1t, d_b1, dW2t, d_b2, x_rec, X, Y, r0, wave, lrow, lk);
}

// ---- pred decoder (after scan): decoder(tanh(z rows)) -> x_pred ----------
__launch_bounds__(512, 4)
__global__ void pred_dec_kernel(const float* __restrict__ zin,
                                const unsigned short* __restrict__ dW0t, const float* __restrict__ d_b0,
                                const unsigned short* __restrict__ dW1t, const float* __restrict__ d_b1,
                                const unsigned short* __restrict__ dW2t, const float* __restrict__ d_b2,
                                float* __restrict__ x_pred) {
  __shared__ __align__(16) char X[M_ * 256];
  __shared__ __align__(16) char Y[M_ * 512];

  const int tid  = threadIdx.x;
  const int wave = tid >> 6;
  const int lane = tid & 63;
  const int lrow = lane & 15;
  const int lk   = lane >> 4;
  const int r0   = blockIdx.x * M_;

  stage<MODE_TANH>(zin, X, nullptr, r0, tid);   // input @X str 256
  __syncthreads();
  dec_body<MODE_TANH>(dW0t, d_b0, dW1t, d_b1, dW2t, d_b2, x_pred, X, Y, r0, wave, lrow, lk);
}

// ---- fused weight prep: all six fp32 [K][N] -> bf16 [N][K] ---------------
__global__ void wprep_all_kernel(const float* __restrict__ s0, const float* __restrict__ s1,
                                 const float* __restrict__ s2, const float* __restrict__ s3,
                                 const float* __restrict__ s4, const float* __restrict__ s5,
                                 unsigned short* __restrict__ d0, unsigned short* __restrict__ d1,
                                 unsigned short* __restrict__ d2, unsigned short* __restrict__ d3,
                                 unsigned short* __restrict__ d4, unsigned short* __restrict__ d5) {
  const int id = blockIdx.x * blockDim.x + threadIdx.x;
  const float* src; unsigned short* dst; int K, N, l;
  if (id < 65536)       { src = s0; dst = d0; K = 128; N = 512; l = id; }
  else if (id < 196608) { src = s1; dst = d1; K = 512; N = 256; l = id - 65536; }
  else if (id < 229376) { src = s2; dst = d2; K = 256; N = 128; l = id - 196608; }
  else if (id < 262144) { src = s3; dst = d3; K = 128; N = 256; l = id - 229376; }
  else if (id < 393216) { src = s4; dst = d4; K = 256; N = 512; l = id - 262144; }
  else                  { src = s5; dst = d5; K = 512; N = 128; l = id - 393216; }
  const int k = l / N;
  const int n = l - k * N;
  dst[(size_t)n * K + k] = f2bf(src[l]);
}

// ---- RNN scan (fp32, sequential, tiny) ----------------------------------
__global__ void rnn_scan_kernel(const float* __restrict__ noise,
                                const float* __restrict__ m, const float* __restrict__ n,
                                float* __restrict__ z) {
  const int gtid = blockIdx.x * blockDim.x + threadIdx.x;
  const int b = gtid >> 6;
  const int lane = threadIdx.x & 63;
  const int k0 = lane, k1 = lane + 64;

  const float mk00 = m[k0 * 2], mk01 = m[k0 * 2 + 1];
  const float mk10 = m[k1 * 2], mk11 = m[k1 * 2 + 1];
  const float nk00 = n[k0 * 2], nk01 = n[k0 * 2 + 1];
  const float nk10 = n[k1 * 2], nk11 = n[k1 * 2 + 1];

  float* zb = z + (size_t)b * T_ * D_;
  const float* nzb = noise + (size_t)b * (T_ - 1) * D_;
  float h0 = zb[k0];
  float h1 = zb[k1];

#pragma unroll 1
  for (int t = 0; t < T_ - 1; ++t) {
    const float r0v = tanhf(h0);
    const float r1v = tanhf(h1);
    float p0 = r0v * nk00 + r1v * nk10;
    float p1 = r0v * nk01 + r1v * nk11;
#pragma unroll
    for (int off = 32; off > 0; off >>= 1) {
      p0 += __shfl_xor(p0, off);
      p1 += __shfl_xor(p1, off);
    }
    const float v0 = (p0 * mk00 + p1 * mk01) * (1.0f / 128.0f);
    const float v1 = (p0 * mk10 + p1 * mk11) * (1.0f / 128.0f);
    const float nz0 = nzb[t * D_ + k0];
    const float nz1 = nzb[t * D_ + k1];
    h0 += 0.2f * (v0 - h0) + 0.05f * nz0;
    h1 += 0.2f * (v1 - h1) + 0.05f * nz1;
    zb[(t + 1) * D_ + k0] = h0;
    zb[(t + 1) * D_ + k1] = h1;
  }
}

}  // namespace

extern "C" void kernel_launch(void* const* d_in, const int* in_sizes, int n_in,
                              void* d_out, int out_size, void* d_ws, size_t ws_size,
                              hipStream_t stream) {
  (void)in_sizes; (void)n_in; (void)ws_size; (void)out_size;

  const float* x     = (const float*)d_in[0];
  const float* noise = (const float*)d_in[1];
  const float* e_w0 = (const float*)d_in[3];
  const float* e_b0 = (const float*)d_in[4];
  const float* e_w1 = (const float*)d_in[5];
  const float* e_b1 = (const float*)d_in[6];
  const float* e_w2 = (const float*)d_in[7];
  const float* e_b2 = (const float*)d_in[8];
  const float* d_w0 = (const float*)d_in[9];
  const float* d_b0 = (const float*)d_in[10];
  const float* d_w1 = (const float*)d_in[11];
  const float* d_b1 = (const float*)d_in[12];
  const float* d_w2 = (const float*)d_in[13];
  const float* d_b2 = (const float*)d_in[14];
  const float* m    = (const float*)d_in[15];
  const float* n    = (const float*)d_in[16];

  float* out    = (float*)d_out;
  float* x_pred = out;                          // (B,T,128)
  float* x_rec  = out + (size_t)BT_ * D_;       // (B,T,128)
  float* z      = out + 2 * (size_t)BT_ * D_;   // (B,T,128)

  unsigned short* ws = (unsigned short*)d_ws;
  unsigned short* eW0t = ws;            // 512x128
  unsigned short* eW1t = ws + 65536;    // 256x512
  unsigned short* eW2t = ws + 196608;   // 128x256
  unsigned short* dW0t = ws + 229376;   // 256x128
  unsigned short* dW1t = ws + 262144;   // 512x256
  unsigned short* dW2t = ws + 393216;   // 128x512

  wprep_all_kernel<<<458752 / 256, 256, 0, stream>>>(e_w0, e_w1, e_w2, d_w0, d_w1, d_w2,
                                                     eW0t, eW1t, eW2t, dW0t, dW1t, dW2t);

  // 1) fused encoder + recon decoder: x -> h_enc (z region) + x_reconstruct
  //    (side-writes x_pred[:,0,:] = cleaned x0)
  enc_dec_kernel<<<BT_ / M_, 512, 0, stream>>>(x,
      eW0t, e_b0, eW1t, e_b1, eW2t, e_b2,
      dW0t, d_b0, dW1t, d_b1, dW2t, d_b2,
      z, x_rec, x_pred);

  // 2) RNN scan: z[:,1:,:] = h_1..h_99 (z[:,0,:] already h0)
  rnn_scan_kernel<<<B_ / 4, 256, 0, stream>>>(noise, m, n, z);

  // 3) pred decoder: decoder(tanh(z[:,1:,:])) -> x_pred[:,1:,:]
  pred_dec_kernel<<<(B_ * (T_ - 1)) / M_, 512, 0, stream>>>(z,
      dW0t, d_b0, dW1t, d_b1, dW2t, d_b2, x_pred);
}